// Round 12
// baseline (370.786 us; speedup 1.0000x reference)
//
#include <hip/hip_runtime.h>
#include <hip/hip_bf16.h>
#include <stdint.h>

// B=4, T=2048, C=1024, H=16, HS=64, FF=4096. N_tokens = 8192.

typedef unsigned short u16;
typedef __bf16 bf16x8 __attribute__((ext_vector_type(8)));
typedef float f32x4 __attribute__((ext_vector_type(4)));
typedef float f32x16 __attribute__((ext_vector_type(16)));

#define MFMA16(a, b, c) __builtin_amdgcn_mfma_f32_16x16x32_bf16((a), (b), (c), 0, 0, 0)
#define MFMA32(a, b, c) __builtin_amdgcn_mfma_f32_32x32x16_bf16((a), (b), (c), 0, 0, 0)

__device__ __forceinline__ u16 f2bf(float f) {
  __hip_bfloat16 h = __float2bfloat16(f);
  return __builtin_bit_cast(u16, h);
}

__device__ __forceinline__ float bf2f(u16 u) {
  uint32_t t = (uint32_t)u << 16;
  return __builtin_bit_cast(float, t);
}

__device__ __forceinline__ uint32_t cvtpk(float lo, float hi_) {
  uint32_t r;
  asm("v_cvt_pk_bf16_f32 %0, %1, %2" : "=v"(r) : "v"(lo), "v"(hi_));
  return r;
}

__device__ __forceinline__ void pl32swap(uint32_t& a, uint32_t& b) {
  asm("v_permlane32_swap_b32 %0, %1" : "+v"(a), "+v"(b));
}

__device__ __forceinline__ void gload16(const void* g, void* l) {
  __builtin_amdgcn_global_load_lds(
      (__attribute__((address_space(1))) void*)g,
      (__attribute__((address_space(3))) void*)l, 16, 0, 0);
}

// ---------------- LayerNorm: fp32 [rows][1024] -> bf16 ----------------
__device__ __forceinline__ void ln_body(
    int row, int tid, const float* __restrict__ x, const float* __restrict__ g,
    const float* __restrict__ be, u16* __restrict__ out, float* red) {
  const float4 v = reinterpret_cast<const float4*>(x + (size_t)row * 1024)[tid];
  float s = v.x + v.y + v.z + v.w;
  float s2 = v.x * v.x + v.y * v.y + v.z * v.z + v.w * v.w;
#pragma unroll
  for (int off = 1; off < 64; off <<= 1) {
    s += __shfl_xor(s, off);
    s2 += __shfl_xor(s2, off);
  }
  const int wid = tid >> 6;
  if ((tid & 63) == 0) { red[wid] = s; red[4 + wid] = s2; }
  __syncthreads();
  s = red[0] + red[1] + red[2] + red[3];
  s2 = red[4] + red[5] + red[6] + red[7];
  const float mu = s * (1.0f / 1024.0f);
  const float rstd = rsqrtf(s2 * (1.0f / 1024.0f) - mu * mu + 1e-5f);
  const float4 gv = reinterpret_cast<const float4*>(g)[tid];
  const float4 bv = reinterpret_cast<const float4*>(be)[tid];
  ushort4 o;
  o.x = f2bf((v.x - mu) * rstd * gv.x + bv.x);
  o.y = f2bf((v.y - mu) * rstd * gv.y + bv.y);
  o.z = f2bf((v.z - mu) * rstd * gv.z + bv.z);
  o.w = f2bf((v.w - mu) * rstd * gv.w + bv.w);
  *reinterpret_cast<ushort4*>(out + (size_t)row * 1024 + tid * 4) = o;
}

__global__ __launch_bounds__(256) void ln_kernel(
    const float* __restrict__ x, const float* __restrict__ g,
    const float* __restrict__ be, u16* __restrict__ out) {
  __shared__ float red[8];
  ln_body(blockIdx.x, threadIdx.x, x, g, be, out, red);
}

// ------- prep mega-kernel: ln1 (blocks 0..8191) + all weight transposes -------
__global__ __launch_bounds__(256) void prep(
    const float* __restrict__ x, const float* __restrict__ g1,
    const float* __restrict__ be1, u16* __restrict__ hb,
    const float* __restrict__ Wq, const float* __restrict__ Wk,
    const float* __restrict__ Wv, const float* __restrict__ Wproj,
    const float* __restrict__ W1, const float* __restrict__ W2,
    u16* __restrict__ wqkvt, u16* __restrict__ wprojt,
    u16* __restrict__ w1t, u16* __restrict__ w2t) {
  __shared__ float t[64][65];  // also covers ln's red[8]
  const int tid = threadIdx.x;
  int b = blockIdx.x;
  if (b < 8192) {
    ln_body(b, tid, x, g1, be1, hb, &t[0][0]);
    return;
  }
  b -= 8192;
  const float* src;
  u16* dst;
  int R, C, bx, by;
  if (b < 768) {  // Wq/Wk/Wv: per-head [1024][64] -> [64][1024]
    const int w = b >> 8, r = b & 255;
    const int z = r >> 4;
    src = (w == 0 ? Wq : w == 1 ? Wk : Wv) + (size_t)z * 65536;
    dst = wqkvt + w * 1048576 + (size_t)z * 65536;
    R = 1024; C = 64; bx = r & 15; by = 0;
  } else if (b < 1024) {  // Wproj [1024][1024]
    const int r = b - 768;
    src = Wproj; dst = wprojt; R = 1024; C = 1024; bx = r & 15; by = r >> 4;
  } else if (b < 2048) {  // W1 [1024][4096]
    const int r = b - 1024;
    src = W1; dst = w1t; R = 1024; C = 4096; bx = r & 15; by = r >> 4;
  } else {  // W2 [4096][1024]
    const int r = b - 2048;
    src = W2; dst = w2t; R = 4096; C = 1024; bx = r & 63; by = r >> 6;
  }
  const int r0 = bx * 64, c0 = by * 64;
  const int cc = tid & 63, rr = tid >> 6;
#pragma unroll
  for (int p = 0; p < 16; ++p) {
    const int r = rr + p * 4;
    t[r][cc] = src[(size_t)(r0 + r) * C + c0 + cc];
  }
  __syncthreads();
#pragma unroll
  for (int p = 0; p < 16; ++p) {
    const int c = rr + p * 4;
    dst[(size_t)(c0 + c) * R + r0 + cc] = f2bf(t[cc][c]);
  }
}

// ---------------- FF2 split-K combine: out += p0 + p1 + b2 ----------------
__global__ __launch_bounds__(256) void ff2_combine(
    const u16* __restrict__ p0, const u16* __restrict__ p1,
    const float* __restrict__ b2, float* __restrict__ out) {
  const size_t base = ((size_t)blockIdx.x * 256 + threadIdx.x) * 8;
  const uint4 a0 = *reinterpret_cast<const uint4*>(p0 + base);
  const uint4 a1 = *reinterpret_cast<const uint4*>(p1 + base);
  const u16* e0 = reinterpret_cast<const u16*>(&a0);
  const u16* e1 = reinterpret_cast<const u16*>(&a1);
  const int c = (int)(base & 1023);
  const float4 bv0 = *reinterpret_cast<const float4*>(b2 + c);
  const float4 bv1 = *reinterpret_cast<const float4*>(b2 + c + 4);
  float4 o0 = *reinterpret_cast<const float4*>(out + base);
  float4 o1 = *reinterpret_cast<const float4*>(out + base + 4);
  o0.x += bf2f(e0[0]) + bf2f(e1[0]) + bv0.x;
  o0.y += bf2f(e0[1]) + bf2f(e1[1]) + bv0.y;
  o0.z += bf2f(e0[2]) + bf2f(e1[2]) + bv0.z;
  o0.w += bf2f(e0[3]) + bf2f(e1[3]) + bv0.w;
  o1.x += bf2f(e0[4]) + bf2f(e1[4]) + bv1.x;
  o1.y += bf2f(e0[5]) + bf2f(e1[5]) + bv1.y;
  o1.z += bf2f(e0[6]) + bf2f(e1[6]) + bv1.z;
  o1.w += bf2f(e0[7]) + bf2f(e1[7]) + bv1.w;
  *reinterpret_cast<float4*>(out + base) = o0;
  *reinterpret_cast<float4*>(out + base + 4) = o1;
}

constexpr int EPI_QKV = 0;   // scatter to q/k/v [BH][T][HS] bf16 (q pre-scaled)
constexpr int EPI_RES = 1;   // fp32 out = acc + bias[n] + res[idx]
constexpr int EPI_RELU = 2;  // bf16 out = relu(acc + bias[n])
constexpr int EPI_PART = 3;  // bf16 partial (split-K half)

// ---------------- GEMM 256x256 tile, BK=64, 8 waves, 8-phase schedule ----------
template <int EPI>
__global__ __launch_bounds__(512) void gemm256(
    const u16* __restrict__ A, const u16* __restrict__ Bt,
    int M, int N, int Kloop, int Kstride, int NBN, int SPLIT,
    u16* outB, u16* outB2, float* outF, const float* bias) {
  __shared__ u16 sA[2][256 * 64] __attribute__((aligned(16)));
  __shared__ u16 sB[2][256 * 64] __attribute__((aligned(16)));
  const int tid = threadIdx.x;
  const int lane = tid & 63, wid = tid >> 6;
  const int wr = wid >> 2, wc = wid & 3;     // 2 x 4 wave grid
  const int l16 = lane & 15, lg = lane >> 4;
  const int nwg = gridDim.x;
  const int wgid = (blockIdx.x & 7) * (nwg >> 3) + (blockIdx.x >> 3);
  int wg = wgid, ks = 0;
  if (SPLIT) { ks = wg & 1; wg >>= 1; }
  const int bm = wg / NBN, bn = wg % NBN;
  const u16* Ap = A + (size_t)ks * Kloop;
  const u16* Btp = Bt + (size_t)ks * Kloop;
  u16* outp = (SPLIT && ks) ? outB2 : outB;
  const size_t rowA = (size_t)bm * 256;
  const size_t rowB = (size_t)bn * 256;
  const int nkt = Kloop >> 6;

  f32x4 acc[8][4];
#pragma unroll
  for (int m = 0; m < 8; ++m)
#pragma unroll
    for (int n = 0; n < 4; ++n) {
      acc[m][n][0] = 0.f; acc[m][n][1] = 0.f; acc[m][n][2] = 0.f; acc[m][n][3] = 0.f;
    }

  auto stageA = [&](int kt, int h) {
    if (kt >= nkt) return;
    const int k0 = kt << 6;
    char* base = (char*)&sA[kt & 1][h * 8192];
#pragma unroll
    for (int it = 0; it < 2; ++it) {
      const int f = tid + it * 512;
      const int r = f >> 3, c = f & 7;
      gload16(Ap + (rowA + h * 128 + r) * Kstride + k0 + ((c ^ (r & 7)) << 3), base + f * 16);
    }
  };
  auto stageB = [&](int kt, int h) {
    if (kt >= nkt) return;
    const int k0 = kt << 6;
    char* base = (char*)&sB[kt & 1][h * 8192];
#pragma unroll
    for (int it = 0; it < 2; ++it) {
      const int f = tid + it * 512;
      const int r = f >> 3, c = f & 7;
      gload16(Btp + (rowB + h * 128 + r) * Kstride + k0 + ((c ^ (r & 7)) << 3), base + f * 16);
    }
  };

  stageA(0, 0); stageB(0, 0); stageA(0, 1); stageB(0, 1);
  stageB(1, 0); stageA(1, 0);
  asm volatile("s_waitcnt vmcnt(4)" ::: "memory");
  __builtin_amdgcn_s_barrier();
  asm volatile("" ::: "memory");

  bf16x8 a[4][2], b[4][2];
  for (int kt = 0; kt < nkt; ++kt) {
    const u16* bufA = &sA[kt & 1][0];
    const u16* bufB = &sB[kt & 1][0];
#pragma unroll
    for (int m = 0; m < 4; ++m)
#pragma unroll
      for (int kk = 0; kk < 2; ++kk) {
        const int r = wr * 128 + m * 16 + l16;
        a[m][kk] = *reinterpret_cast<const bf16x8*>(bufA + r * 64 + (((kk * 4 + lg) ^ (r & 7)) << 3));
      }
#pragma unroll
    for (int n = 0; n < 2; ++n)
#pragma unroll
      for (int kk = 0; kk < 2; ++kk) {
        const int r = wc * 64 + n * 16 + l16;
        b[n][kk] = *reinterpret_cast<const bf16x8*>(bufB + r * 64 + (((kk * 4 + lg) ^ (r & 7)) << 3));
      }
    stageB(kt + 1, 1);
    __builtin_amdgcn_s_barrier();
    asm volatile("s_waitcnt lgkmcnt(0)" ::: "memory");
    __builtin_amdgcn_s_setprio(1);
#pragma unroll
    for (int kk = 0; kk < 2; ++kk)
#pragma unroll
      for (int m = 0; m < 4; ++m)
#pragma unroll
        for (int n = 0; n < 2; ++n)
          acc[m][n] = MFMA16(a[m][kk], b[n][kk], acc[m][n]);
    __builtin_amdgcn_s_setprio(0);
    __builtin_amdgcn_s_barrier();
    asm volatile("" ::: "memory");
#pragma unroll
    for (int n = 2; n < 4; ++n)
#pragma unroll
      for (int kk = 0; kk < 2; ++kk) {
        const int r = wc * 64 + n * 16 + l16;
        b[n][kk] = *reinterpret_cast<const bf16x8*>(bufB + r * 64 + (((kk * 4 + lg) ^ (r & 7)) << 3));
      }
    stageA(kt + 1, 1);
    __builtin_amdgcn_s_barrier();
    asm volatile("s_waitcnt lgkmcnt(0)" ::: "memory");
    __builtin_amdgcn_s_setprio(1);
#pragma unroll
    for (int kk = 0; kk < 2; ++kk)
#pragma unroll
      for (int m = 0; m < 4; ++m)
#pragma unroll
        for (int n = 2; n < 4; ++n)
          acc[m][n] = MFMA16(a[m][kk], b[n][kk], acc[m][n]);
    __builtin_amdgcn_s_setprio(0);
    __builtin_amdgcn_s_barrier();
    asm volatile("" ::: "memory");
#pragma unroll
    for (int m = 0; m < 4; ++m)
#pragma unroll
      for (int kk = 0; kk < 2; ++kk) {
        const int r = wr * 128 + 64 + m * 16 + l16;
        a[m][kk] = *reinterpret_cast<const bf16x8*>(bufA + r * 64 + (((kk * 4 + lg) ^ (r & 7)) << 3));
      }
    stageB(kt + 2, 0);
    __builtin_amdgcn_s_barrier();
    asm volatile("s_waitcnt lgkmcnt(0)" ::: "memory");
    __builtin_amdgcn_s_setprio(1);
#pragma unroll
    for (int kk = 0; kk < 2; ++kk)
#pragma unroll
      for (int m = 0; m < 4; ++m)
#pragma unroll
        for (int n = 2; n < 4; ++n)
          acc[4 + m][n] = MFMA16(a[m][kk], b[n][kk], acc[4 + m][n]);
    __builtin_amdgcn_s_setprio(0);
    __builtin_amdgcn_s_barrier();
    asm volatile("" ::: "memory");
    stageA(kt + 2, 0);
    __builtin_amdgcn_s_setprio(1);
#pragma unroll
    for (int kk = 0; kk < 2; ++kk)
#pragma unroll
      for (int m = 0; m < 4; ++m)
#pragma unroll
        for (int n = 0; n < 2; ++n)
          acc[4 + m][n] = MFMA16(a[m][kk], b[n][kk], acc[4 + m][n]);
    __builtin_amdgcn_s_setprio(0);
    if (kt + 2 < nkt) {
      asm volatile("s_waitcnt vmcnt(4)" ::: "memory");
    } else {
      asm volatile("s_waitcnt vmcnt(0)" ::: "memory");  // tail: stages skipped, full drain
    }
    __builtin_amdgcn_s_barrier();
    asm volatile("" ::: "memory");
  }

#pragma unroll
  for (int m = 0; m < 8; ++m)
#pragma unroll
    for (int n = 0; n < 4; ++n)
#pragma unroll
      for (int ii = 0; ii < 4; ++ii) {
        const int gi = bm * 256 + wr * 128 + m * 16 + lg * 4 + ii;
        const int gj = bn * 256 + wc * 64 + n * 16 + l16;
        const float val = acc[m][n][ii];
        if constexpr (EPI == EPI_QKV) {
          const int sel = gj >> 10;          // 0:q 1:k 2:v
          const int hh = (gj >> 6) & 15;
          const int dd = gj & 63;
          const int bb = gi >> 11, tt = gi & 2047;
          const float sv = (sel == 0) ? val * 0.1803368801f : val;
          outB[(size_t)sel * 8388608 + ((size_t)(bb * 16 + hh) * 2048 + tt) * 64 + dd] = f2bf(sv);
        } else if constexpr (EPI == EPI_RELU) {
          const float bv = val + bias[gj];
          outB[(size_t)gi * N + gj] = f2bf(bv > 0.f ? bv : 0.f);
        } else if constexpr (EPI == EPI_PART) {
          outp[(size_t)gi * N + gj] = f2bf(val);
        }
      }
}

// ---------------- GEMM 128x256 tile, BK=64, 8 waves, 8-phase (proj) ------
template <int EPI>
__global__ __launch_bounds__(512) void gemm128(
    const u16* __restrict__ A, const u16* __restrict__ Bt,
    int M, int N, int K, int NBN,
    u16* outB, float* outF, const float* bias, const float* res) {
  __shared__ u16 sA[2][128 * 64] __attribute__((aligned(16)));  // 32KB
  __shared__ u16 sB[2][256 * 64] __attribute__((aligned(16)));  // 64KB
  const int tid = threadIdx.x;
  const int lane = tid & 63, wid = tid >> 6;
  const int wr = wid >> 2, wc = wid & 3;  // 2 x 4 wave grid; wave out 64x64
  const int l16 = lane & 15, lg = lane >> 4;
  const int nwg = gridDim.x;
  const int wgid = (blockIdx.x & 7) * (nwg >> 3) + (blockIdx.x >> 3);
  const int bm = wgid / NBN, bn = wgid % NBN;
  const size_t rowA = (size_t)bm * 128;
  const size_t rowB = (size_t)bn * 256;
  const int nkt = K >> 6;

  f32x4 acc[4][4];
#pragma unroll
  for (int m = 0; m < 4; ++m)
#pragma unroll
    for (int n = 0; n < 4; ++n) {
      acc[m][n][0] = 0.f; acc[m][n][1] = 0.f; acc[m][n][2] = 0.f; acc[m][n][3] = 0.f;
    }

  auto stageA = [&](int kt, int h) {  // 64 rows x 64 cols: 1 load/thread
    if (kt >= nkt) return;
    const int k0 = kt << 6;
    char* base = (char*)&sA[kt & 1][h * 4096];
    const int r = tid >> 3, c = tid & 7;
    gload16(A + (rowA + h * 64 + r) * K + k0 + ((c ^ (r & 7)) << 3), base + tid * 16);
  };
  auto stageB = [&](int kt, int h) {  // 128 rows x 64 cols: 2 loads/thread
    if (kt >= nkt) return;
    const int k0 = kt << 6;
    char* base = (char*)&sB[kt & 1][h * 8192];
#pragma unroll
    for (int it = 0; it < 2; ++it) {
      const int f = tid + it * 512;
      const int r = f >> 3, c = f & 7;
      gload16(Bt + (rowB + h * 128 + r) * K + k0 + ((c ^ (r & 7)) << 3), base + f * 16);
    }
  };

  stageA(0, 0); stageB(0, 0); stageA(0, 1); stageB(0, 1);
  stageB(1, 0); stageA(1, 0);
  asm volatile("s_waitcnt vmcnt(3)" ::: "memory");
  __builtin_amdgcn_s_barrier();
  asm volatile("" ::: "memory");

  bf16x8 a[2][2], b[4][2];
  for (int kt = 0; kt < nkt; ++kt) {
    const u16* bufA = &sA[kt & 1][0];
    const u16* bufB = &sB[kt & 1][0];
#pragma unroll
    for (int m = 0; m < 2; ++m)
#pragma unroll
      for (int kk = 0; kk < 2; ++kk) {
        const int r = wr * 64 + m * 16 + l16;
        a[m][kk] = *reinterpret_cast<const bf16x8*>(bufA + r * 64 + (((kk * 4 + lg) ^ (r & 7)) << 3));
      }
#pragma unroll
    for (int n = 0; n < 2; ++n)
#pragma unroll
      for (int kk = 0; kk < 2; ++kk) {
        const int r = wc * 64 + n * 16 + l16;
        b[n][kk] = *reinterpret_cast<const bf16x8*>(bufB + r * 64 + (((kk * 4 + lg) ^ (r & 7)) << 3));
      }
    stageB(kt + 1, 1);
    __builtin_amdgcn_s_barrier();
    asm volatile("s_waitcnt lgkmcnt(0)" ::: "memory");
    __builtin_amdgcn_s_setprio(1);
#pragma unroll
    for (int kk = 0; kk < 2; ++kk)
#pragma unroll
      for (int m = 0; m < 2; ++m)
#pragma unroll
        for (int n = 0; n < 2; ++n)
          acc[m][n] = MFMA16(a[m][kk], b[n][kk], acc[m][n]);
    __builtin_amdgcn_s_setprio(0);
    __builtin_amdgcn_s_barrier();
    asm volatile("" ::: "memory");
#pragma unroll
    for (int n = 2; n < 4; ++n)
#pragma unroll
      for (int kk = 0; kk < 2; ++kk) {
        const int r = wc * 64 + n * 16 + l16;
        b[n][kk] = *reinterpret_cast<const bf16x8*>(bufB + r * 64 + (((kk * 4 + lg) ^ (r & 7)) << 3));
      }
    stageA(kt + 1, 1);
    __builtin_amdgcn_s_barrier();
    asm volatile("s_waitcnt lgkmcnt(0)" ::: "memory");
    __builtin_amdgcn_s_setprio(1);
#pragma unroll
    for (int kk = 0; kk < 2; ++kk)
#pragma unroll
      for (int m = 0; m < 2; ++m)
#pragma unroll
        for (int n = 2; n < 4; ++n)
          acc[m][n] = MFMA16(a[m][kk], b[n][kk], acc[m][n]);
    __builtin_amdgcn_s_setprio(0);
    __builtin_amdgcn_s_barrier();
    asm volatile("" ::: "memory");
#pragma unroll
    for (int m = 0; m < 2; ++m)
#pragma unroll
      for (int kk = 0; kk < 2; ++kk) {
        const int r = wr * 64 + (m + 2) * 16 + l16;
        a[m][kk] = *reinterpret_cast<const bf16x8*>(bufA + r * 64 + (((kk * 4 + lg) ^ (r & 7)) << 3));
      }
    stageB(kt + 2, 0);
    __builtin_amdgcn_s_barrier();
    asm volatile("s_waitcnt lgkmcnt(0)" ::: "memory");
    __builtin_amdgcn_s_setprio(1);
#pragma unroll
    for (int kk = 0; kk < 2; ++kk)
#pragma unroll
      for (int m = 0; m < 2; ++m)
#pragma unroll
        for (int n = 2; n < 4; ++n)
          acc[2 + m][n] = MFMA16(a[m][kk], b[n][kk], acc[2 + m][n]);
    __builtin_amdgcn_s_setprio(0);
    __builtin_amdgcn_s_barrier();
    asm volatile("" ::: "memory");
    stageA(kt + 2, 0);
    __builtin_amdgcn_s_setprio(1);
#pragma unroll
    for (int kk = 0; kk < 2; ++kk)
#pragma unroll
      for (int m = 0; m < 2; ++m)
#pragma unroll
        for (int n = 0; n < 2; ++n)
          acc[2 + m][n] = MFMA16(a[m][kk], b[n][kk], acc[2 + m][n]);
    __builtin_amdgcn_s_setprio(0);
    if (kt + 2 < nkt) {
      asm volatile("s_waitcnt vmcnt(3)" ::: "memory");
    } else {
      asm volatile("s_waitcnt vmcnt(0)" ::: "memory");  // tail: full drain
    }
    __builtin_amdgcn_s_barrier();
    asm volatile("" ::: "memory");
  }

#pragma unroll
  for (int m = 0; m < 4; ++m)
#pragma unroll
    for (int n = 0; n < 4; ++n)
#pragma unroll
      for (int ii = 0; ii < 4; ++ii) {
        const int gi = bm * 128 + wr * 64 + m * 16 + lg * 4 + ii;
        const int gj = bn * 256 + wc * 64 + n * 16 + l16;
        const float val = acc[m][n][ii];
        if constexpr (EPI == EPI_RES) {
          const size_t idx = (size_t)gi * N + gj;
          outF[idx] = val + bias[gj] + res[idx];
        }
      }
}

// ---------------- causal flash attention v9: causal-fold paired strips ----------
// Block handles q-strips {p, 15-p} sequentially -> uniform 34 steps/block.
// Grid 512 (8 pairs x 64 bh, XCD bh-grouping), 2 blocks/CU, no drain-out tail.
// Inner body identical to v8 (T13 defer-max, li-via-MFMA, tree max, setprio).
__global__ __launch_bounds__(256, 3) void attn_kernel(
    const u16* __restrict__ q, const u16* __restrict__ k,
    const u16* __restrict__ v, u16* __restrict__ o) {
  const int bid = blockIdx.x;
  const int bh = (bid & 7) * 8 + ((bid >> 3) & 7);  // 8 bh per XCD -> K/V L2-resident
  const int pr = bid >> 6;                          // pair index 0..7
  const int tid = threadIdx.x;
  const int lane = tid & 63, wid = tid >> 6;
  const int l32 = lane & 31, hi = lane >> 5;
  const u16* qb = q + (size_t)bh * (2048 * 64);
  const u16* kb = k + (size_t)bh * (2048 * 64);
  const u16* vb = v + (size_t)bh * (2048 * 64);

  __shared__ u16 sK[2][64 * 64] __attribute__((aligned(16)));   // chunk-xor swizzled
  __shared__ u16 sVt[2][64 * 72] __attribute__((aligned(16)));  // V^T [d][kv], pad 72

  // ones-row A fragment for the li-sum MFMA (row 0 of the 32x32 tile)
  bf16x8 aone;
  {
    union { u16 u[8]; bf16x8 v; } onec;
    const u16 ov = (l32 == 0) ? (u16)0x3F80 : (u16)0;
#pragma unroll
    for (int j = 0; j < 8; ++j) onec.u[j] = ov;
    aone = onec.v;
  }

  uint4 vr0, vr1;  // V staging regs

  auto stageK = [&](int s0, int buf) {
#pragma unroll
    for (int it = 0; it < 2; ++it) {
      const int f = tid + it * 256;  // 16B-chunk index in [64][8]
      const int r = f >> 3, c = f & 7;
      gload16(kb + (size_t)(s0 + r) * 64 + (size_t)((c ^ (r & 7)) * 8),
              (char*)&sK[buf][0] + it * 4096 + wid * 1024);
    }
  };
  auto loadV = [&](int s0) {
    const int kvp = tid & 31;  // kv row-pair
    const int c8 = tid >> 5;   // d-chunk
    vr0 = *reinterpret_cast<const uint4*>(vb + (size_t)(s0 + 2 * kvp) * 64 + c8 * 8);
    vr1 = *reinterpret_cast<const uint4*>(vb + (size_t)(s0 + 2 * kvp + 1) * 64 + c8 * 8);
  };
  auto writeV = [&](int buf) {
    const int kvp = tid & 31;
    const int c8 = tid >> 5;
    const u16* e0 = reinterpret_cast<const u16*>(&vr0);
    const u16* e1 = reinterpret_cast<const u16*>(&vr1);
    u16* base = &sVt[buf][0];
#pragma unroll
    for (int j = 0; j < 8; ++j) {
      const int d = c8 * 8 + j;
      *reinterpret_cast<uint32_t*>(base + d * 72 + 2 * kvp) =
          (uint32_t)e0[j] | ((uint32_t)e1[j] << 16);
    }
  };

  for (int half = 0; half < 2; ++half) {
    const int qt = half ? (15 - pr) : pr;
    const int q0 = qt * 128;
    const int qrow = q0 + wid * 32 + l32;  // this lane's q row

    bf16x8 bq[4];
#pragma unroll
    for (int s = 0; s < 4; ++s)
      bq[s] = *reinterpret_cast<const bf16x8*>(qb + (size_t)qrow * 64 + s * 16 + hi * 8);

    f32x16 oacc[2], osum;
#pragma unroll
    for (int r = 0; r < 16; ++r) { oacc[0][r] = 0.f; oacc[1][r] = 0.f; osum[r] = 0.f; }
    float mi = -1e30f;

    const int nst = 2 * qt + 2;  // always even, >= 2
    stageK(0, 0);
    loadV(0);
    asm volatile("s_waitcnt vmcnt(0)" ::: "memory");
    writeV(0);
    __syncthreads();

    int cur = 0;
    for (int ks = 0; ks < nst; ++ks) {
      const int s0 = ks * 64;
      const int nxt = cur ^ 1;
      if (ks + 1 < nst) { stageK(s0 + 64, nxt); loadV(s0 + 64); }

      // ---- S^T = K Q^T ----
      f32x16 st[2];
#pragma unroll
      for (int r = 0; r < 16; ++r) { st[0][r] = 0.f; st[1][r] = 0.f; }
      __builtin_amdgcn_s_setprio(1);
#pragma unroll
      for (int t = 0; t < 2; ++t) {
        const int row = t * 32 + l32;
        const int rx = row & 7;
#pragma unroll
        for (int s = 0; s < 4; ++s) {
          bf16x8 ak = *reinterpret_cast<const bf16x8*>(
              &sK[cur][0] + row * 64 + (((s * 2 + hi) ^ rx) << 3));
          st[t] = MFMA32(ak, bq[s], st[t]);
        }
      }
      __builtin_amdgcn_s_setprio(0);

      // ---- causal mask (only near diagonal) ----
      if (ks >= 2 * qt) {
#pragma unroll
        for (int t = 0; t < 2; ++t)
#pragma unroll
          for (int a = 0; a < 4; ++a)
#pragma unroll
            for (int c2 = 0; c2 < 4; ++c2) {
              const int kvg = s0 + t * 32 + a * 8 + hi * 4 + c2;
              if (kvg > qrow) st[t][a * 4 + c2] = -1e30f;
            }
      }

      // ---- online softmax: tree max; T13 defer-max (THR=8, exp2 domain) ----
      float tm[16];
#pragma unroll
      for (int r = 0; r < 16; ++r) tm[r] = fmaxf(st[0][r], st[1][r]);
#pragma unroll
      for (int s2 = 8; s2 >= 1; s2 >>= 1)
#pragma unroll
        for (int r = 0; r < s2; ++r) tm[r] = fmaxf(tm[r], tm[r + s2]);
      const float pm = fmaxf(tm[0], __shfl_xor(tm[0], 32));
      if (__any(pm > mi + 8.0f)) {
        const float mn = fmaxf(mi, pm);
        const float al = exp2f(mi - mn);
        mi = mn;
        osum[0] *= al;
#pragma unroll
        for (int dt = 0; dt < 2; ++dt)
#pragma unroll
          for (int r = 0; r < 16; ++r) oacc[dt][r] *= al;
      }
#pragma unroll
      for (int t = 0; t < 2; ++t)
#pragma unroll
        for (int r = 0; r < 16; ++r) st[t][r] = exp2f(st[t][r] - mi);

      // ---- P^T -> bf16 B-frags in-register; PV + li-sum via MFMA ----
      uint32_t W[2][4][2];
#pragma unroll
      for (int t = 0; t < 2; ++t)
#pragma unroll
        for (int a = 0; a < 4; ++a) {
          W[t][a][0] = cvtpk(st[t][a * 4 + 0], st[t][a * 4 + 1]);
          W[t][a][1] = cvtpk(st[t][a * 4 + 2], st[t][a * 4 + 3]);
        }
      __builtin_amdgcn_s_setprio(1);
#pragma unroll
      for (int ks2 = 0; ks2 < 4; ++ks2) {
        const int t = ks2 >> 1;
        uint32_t A0 = W[t][(2 * ks2) & 3][0], B0 = W[t][(2 * ks2 + 1) & 3][0];
        uint32_t A1 = W[t][(2 * ks2) & 3][1], B1 = W[t][(2 * ks2 + 1) & 3][1];
        pl32swap(A0, B0);
        pl32swap(A1, B1);
        union { uint32_t w[4]; bf16x8 v; } bp;
        bp.w[0] = A0; bp.w[1] = A1; bp.w[2] = B0; bp.w[3] = B1;
#pragma unroll
        for (int dt = 0; dt < 2; ++dt) {
          bf16x8 av = *reinterpret_cast<const bf16x8*>(
              &sVt[cur][0] + (dt * 32 + l32) * 72 + ks2 * 16 + hi * 8);
          oacc[dt] = MFMA32(av, bp.v, oacc[dt]);
        }
        osum = MFMA32(aone, bp.v, osum);  // row 0 = sum_kv P -> li
      }
      __builtin_amdgcn_s_setprio(0);

      if (ks + 1 < nst) {
        asm volatile("s_waitcnt vmcnt(0)" ::: "memory");  // K gload_lds + V regs landed
        writeV(nxt);
        __syncthreads();
      }
      cur = nxt;
    }
    // NOTE: last step used buffers [1] (nst even); next half's prologue writes
    // buffers [0] -> no cross-wave race without a trailing barrier.

    // ---- epilogue: O^T regs -> [B,T,C] bf16, /li ----
    const float li = __shfl(osum[0], l32);  // row 0, col q=l32 lives in lane l32
    const int bb = bh >> 4, hh = bh & 15;
    const float rli = 1.0f / li;
    const size_t rowo = (size_t)(bb * 2048 + qrow) * 1024;
#pragma unroll
    for (int dt = 0; dt < 2; ++dt)
#pragma unroll
      for (int a = 0; a < 4; ++a) {
        ushort4 pk;
        pk.x = f2bf(oacc[dt][a * 4 + 0] * rli);
        pk.y = f2bf(oacc[dt][a * 4 + 1] * rli);
        pk.z = f2bf(oacc[dt][a * 4 + 2] * rli);
        pk.w = f2bf(oacc[dt][a * 4 + 3] * rli);
        *reinterpret_cast<ushort4*>(o + rowo + hh * 64 + dt * 32 + a * 8 + hi * 4) = pk;
      }
  }
}

// ---------------- host launch ----------------
extern "C" void kernel_launch(void* const* d_in, const int* in_sizes, int n_in,
                              void* d_out, int out_size, void* d_ws, size_t ws_size,
                              hipStream_t stream) {
  const float* x = (const float*)d_in[0];
  const float* Wq = (const float*)d_in[1];
  const float* Wk = (const float*)d_in[2];
  const float* Wv = (const float*)d_in[3];
  const float* Wproj = (const float*)d_in[4];
  const float* bproj = (const float*)d_in[5];
  const float* W1 = (const float*)d_in[6];
  const float* b1 = (const float*)d_in[7];
  const float* W2 = (const float*)d_in[8];
  const float* b2 = (const float*)d_in[9];
  const float* g1 = (const float*)d_in[10];
  const float* be1 = (const float*)d_in[11];
  const float* g2 = (const float*)d_in[12];
  const float* be2 = (const float*)d_in[13];
  float* out = (float*)d_out;

  char* ws = (char*)d_ws;
  const size_t MB16 = 16777216ull;
  u16* hb = (u16*)(ws);                 // 16MB: ln out (reused for ln2 out)
  u16* qkv = (u16*)(ws + MB16);         // 48MB: q,k,v each 8388608 elems
  u16* qp = qkv;
  u16* kp = qkv + 8388608;
  u16* vp = qkv + 2 * 8388608;
  u16* ab = (u16*)(ws + 4 * MB16);      // 16MB: attention out [B,T,C]
  u16* f1 = qkv;                        // 64MB reuse (16MB..80MB) for relu(ff1)
  u16* wqkvt = (u16*)(ws + 5 * MB16);   // 6MB  [3072][1024]
  u16* wprojt = wqkvt + 3145728;        // 2MB  [1024][1024]
  u16* w1t = wprojt + 1048576;          // 8MB  [4096][1024]
  u16* w2t = w1t + 4194304;             // 8MB  [1024][4096]
  // split-K partials (live only during FF2; alias buffers dead by then)
  u16* p0 = hb;                         // 16MB (hb dead after FF1 reads it)
  u16* p1 = wqkvt;                      // 16MB (wqkvt+wprojt+w1t dead after FF1)

  dim3 blk(256);
  // fused: ln1 (8192 blocks) + all weight transposes (3072 blocks)
  prep<<<11264, blk, 0, stream>>>(x, g1, be1, hb, Wq, Wk, Wv, Wproj, W1, W2,
                                  wqkvt, wprojt, w1t, w2t);
  gemm256<EPI_QKV><<<384, 512, 0, stream>>>(hb, wqkvt, 8192, 3072, 1024, 1024, 12, 0,
                                            qkv, nullptr, nullptr, nullptr);
  attn_kernel<<<512, blk, 0, stream>>>(qp, kp, vp, ab);
  gemm128<EPI_RES><<<256, 512, 0, stream>>>(ab, wprojt, 8192, 1024, 1024, 4,
                                            nullptr, out, bproj, x);
  ln_kernel<<<8192, blk, 0, stream>>>(out, g2, be2, hb);
  gemm256<EPI_RELU><<<512, 512, 0, stream>>>(hb, w1t, 8192, 4096, 1024, 1024, 16, 0,
                                             f1, nullptr, nullptr, b1);
  // FF2 split-K: two K=2048 halves at full occupancy, bf16 partials, then combine
  gemm256<EPI_PART><<<256, 512, 0, stream>>>(f1, w2t, 8192, 1024, 2048, 4096, 4, 1,
                                             p0, p1, nullptr, nullptr);
  ff2_combine<<<4096, blk, 0, stream>>>(p0, p1, b2, out);
}

// Round 13
// 358.023 us; speedup vs baseline: 1.0356x; 1.0356x over previous
//
#include <hip/hip_runtime.h>
#include <hip/hip_bf16.h>
#include <stdint.h>

// B=4, T=2048, C=1024, H=16, HS=64, FF=4096. N_tokens = 8192.

typedef unsigned short u16;
typedef __bf16 bf16x8 __attribute__((ext_vector_type(8)));
typedef float f32x4 __attribute__((ext_vector_type(4)));
typedef float f32x16 __attribute__((ext_vector_type(16)));

#define MFMA16(a, b, c) __builtin_amdgcn_mfma_f32_16x16x32_bf16((a), (b), (c), 0, 0, 0)
#define MFMA32(a, b, c) __builtin_amdgcn_mfma_f32_32x32x16_bf16((a), (b), (c), 0, 0, 0)

__device__ __forceinline__ u16 f2bf(float f) {
  __hip_bfloat16 h = __float2bfloat16(f);
  return __builtin_bit_cast(u16, h);
}

__device__ __forceinline__ float bf2f(u16 u) {
  uint32_t t = (uint32_t)u << 16;
  return __builtin_bit_cast(float, t);
}

__device__ __forceinline__ uint32_t cvtpk(float lo, float hi_) {
  uint32_t r;
  asm("v_cvt_pk_bf16_f32 %0, %1, %2" : "=v"(r) : "v"(lo), "v"(hi_));
  return r;
}

__device__ __forceinline__ void pl32swap(uint32_t& a, uint32_t& b) {
  asm("v_permlane32_swap_b32 %0, %1" : "+v"(a), "+v"(b));
}

__device__ __forceinline__ void gload16(const void* g, void* l) {
  __builtin_amdgcn_global_load_lds(
      (__attribute__((address_space(1))) void*)g,
      (__attribute__((address_space(3))) void*)l, 16, 0, 0);
}

// ---------------- LayerNorm: fp32 [rows][1024] -> bf16 ----------------
__device__ __forceinline__ void ln_body(
    int row, int tid, const float* __restrict__ x, const float* __restrict__ g,
    const float* __restrict__ be, u16* __restrict__ out, float* red) {
  const float4 v = reinterpret_cast<const float4*>(x + (size_t)row * 1024)[tid];
  float s = v.x + v.y + v.z + v.w;
  float s2 = v.x * v.x + v.y * v.y + v.z * v.z + v.w * v.w;
#pragma unroll
  for (int off = 1; off < 64; off <<= 1) {
    s += __shfl_xor(s, off);
    s2 += __shfl_xor(s2, off);
  }
  const int wid = tid >> 6;
  if ((tid & 63) == 0) { red[wid] = s; red[4 + wid] = s2; }
  __syncthreads();
  s = red[0] + red[1] + red[2] + red[3];
  s2 = red[4] + red[5] + red[6] + red[7];
  const float mu = s * (1.0f / 1024.0f);
  const float rstd = rsqrtf(s2 * (1.0f / 1024.0f) - mu * mu + 1e-5f);
  const float4 gv = reinterpret_cast<const float4*>(g)[tid];
  const float4 bv = reinterpret_cast<const float4*>(be)[tid];
  ushort4 o;
  o.x = f2bf((v.x - mu) * rstd * gv.x + bv.x);
  o.y = f2bf((v.y - mu) * rstd * gv.y + bv.y);
  o.z = f2bf((v.z - mu) * rstd * gv.z + bv.z);
  o.w = f2bf((v.w - mu) * rstd * gv.w + bv.w);
  *reinterpret_cast<ushort4*>(out + (size_t)row * 1024 + tid * 4) = o;
}

__global__ __launch_bounds__(256) void ln_kernel(
    const float* __restrict__ x, const float* __restrict__ g,
    const float* __restrict__ be, u16* __restrict__ out) {
  __shared__ float red[8];
  ln_body(blockIdx.x, threadIdx.x, x, g, be, out, red);
}

// ------- prep mega-kernel: ln1 (blocks 0..8191) + all weight transposes -------
__global__ __launch_bounds__(256) void prep(
    const float* __restrict__ x, const float* __restrict__ g1,
    const float* __restrict__ be1, u16* __restrict__ hb,
    const float* __restrict__ Wq, const float* __restrict__ Wk,
    const float* __restrict__ Wv, const float* __restrict__ Wproj,
    const float* __restrict__ W1, const float* __restrict__ W2,
    u16* __restrict__ wqkvt, u16* __restrict__ wprojt,
    u16* __restrict__ w1t, u16* __restrict__ w2t) {
  __shared__ float t[64][65];  // also covers ln's red[8]
  const int tid = threadIdx.x;
  int b = blockIdx.x;
  if (b < 8192) {
    ln_body(b, tid, x, g1, be1, hb, &t[0][0]);
    return;
  }
  b -= 8192;
  const float* src;
  u16* dst;
  int R, C, bx, by;
  if (b < 768) {  // Wq/Wk/Wv: per-head [1024][64] -> [64][1024]
    const int w = b >> 8, r = b & 255;
    const int z = r >> 4;
    src = (w == 0 ? Wq : w == 1 ? Wk : Wv) + (size_t)z * 65536;
    dst = wqkvt + w * 1048576 + (size_t)z * 65536;
    R = 1024; C = 64; bx = r & 15; by = 0;
  } else if (b < 1024) {  // Wproj [1024][1024]
    const int r = b - 768;
    src = Wproj; dst = wprojt; R = 1024; C = 1024; bx = r & 15; by = r >> 4;
  } else if (b < 2048) {  // W1 [1024][4096]
    const int r = b - 1024;
    src = W1; dst = w1t; R = 1024; C = 4096; bx = r & 15; by = r >> 4;
  } else {  // W2 [4096][1024]
    const int r = b - 2048;
    src = W2; dst = w2t; R = 4096; C = 1024; bx = r & 63; by = r >> 6;
  }
  const int r0 = bx * 64, c0 = by * 64;
  const int cc = tid & 63, rr = tid >> 6;
#pragma unroll
  for (int p = 0; p < 16; ++p) {
    const int r = rr + p * 4;
    t[r][cc] = src[(size_t)(r0 + r) * C + c0 + cc];
  }
  __syncthreads();
#pragma unroll
  for (int p = 0; p < 16; ++p) {
    const int c = rr + p * 4;
    dst[(size_t)(c0 + c) * R + r0 + cc] = f2bf(t[cc][c]);
  }
}

// ---------------- FF2 split-K combine: out += p0 + p1 + b2 ----------------
__global__ __launch_bounds__(256) void ff2_combine(
    const u16* __restrict__ p0, const u16* __restrict__ p1,
    const float* __restrict__ b2, float* __restrict__ out) {
  const size_t base = ((size_t)blockIdx.x * 256 + threadIdx.x) * 8;
  const uint4 a0 = *reinterpret_cast<const uint4*>(p0 + base);
  const uint4 a1 = *reinterpret_cast<const uint4*>(p1 + base);
  const u16* e0 = reinterpret_cast<const u16*>(&a0);
  const u16* e1 = reinterpret_cast<const u16*>(&a1);
  const int c = (int)(base & 1023);
  const float4 bv0 = *reinterpret_cast<const float4*>(b2 + c);
  const float4 bv1 = *reinterpret_cast<const float4*>(b2 + c + 4);
  float4 o0 = *reinterpret_cast<const float4*>(out + base);
  float4 o1 = *reinterpret_cast<const float4*>(out + base + 4);
  o0.x += bf2f(e0[0]) + bf2f(e1[0]) + bv0.x;
  o0.y += bf2f(e0[1]) + bf2f(e1[1]) + bv0.y;
  o0.z += bf2f(e0[2]) + bf2f(e1[2]) + bv0.z;
  o0.w += bf2f(e0[3]) + bf2f(e1[3]) + bv0.w;
  o1.x += bf2f(e0[4]) + bf2f(e1[4]) + bv1.x;
  o1.y += bf2f(e0[5]) + bf2f(e1[5]) + bv1.y;
  o1.z += bf2f(e0[6]) + bf2f(e1[6]) + bv1.z;
  o1.w += bf2f(e0[7]) + bf2f(e1[7]) + bv1.w;
  *reinterpret_cast<float4*>(out + base) = o0;
  *reinterpret_cast<float4*>(out + base + 4) = o1;
}

constexpr int EPI_QKV = 0;   // scatter to q/k/v [BH][T][HS] bf16 (q pre-scaled)
constexpr int EPI_RES = 1;   // fp32 out = acc + bias[n] + res[idx]
constexpr int EPI_RELU = 2;  // bf16 out = relu(acc + bias[n])
constexpr int EPI_PART = 3;  // bf16 partial (split-K half)

// ---------------- GEMM 256x256 tile, BK=64, 8 waves, 8-phase schedule ----------
template <int EPI>
__global__ __launch_bounds__(512) void gemm256(
    const u16* __restrict__ A, const u16* __restrict__ Bt,
    int M, int N, int Kloop, int Kstride, int NBN, int SPLIT,
    u16* outB, u16* outB2, float* outF, const float* bias) {
  __shared__ u16 sA[2][256 * 64] __attribute__((aligned(16)));
  __shared__ u16 sB[2][256 * 64] __attribute__((aligned(16)));
  const int tid = threadIdx.x;
  const int lane = tid & 63, wid = tid >> 6;
  const int wr = wid >> 2, wc = wid & 3;     // 2 x 4 wave grid
  const int l16 = lane & 15, lg = lane >> 4;
  const int nwg = gridDim.x;
  const int wgid = (blockIdx.x & 7) * (nwg >> 3) + (blockIdx.x >> 3);
  int wg = wgid, ks = 0;
  if (SPLIT) { ks = wg & 1; wg >>= 1; }
  const int bm = wg / NBN, bn = wg % NBN;
  const u16* Ap = A + (size_t)ks * Kloop;
  const u16* Btp = Bt + (size_t)ks * Kloop;
  u16* outp = (SPLIT && ks) ? outB2 : outB;
  const size_t rowA = (size_t)bm * 256;
  const size_t rowB = (size_t)bn * 256;
  const int nkt = Kloop >> 6;

  f32x4 acc[8][4];
#pragma unroll
  for (int m = 0; m < 8; ++m)
#pragma unroll
    for (int n = 0; n < 4; ++n) {
      acc[m][n][0] = 0.f; acc[m][n][1] = 0.f; acc[m][n][2] = 0.f; acc[m][n][3] = 0.f;
    }

  auto stageA = [&](int kt, int h) {
    if (kt >= nkt) return;
    const int k0 = kt << 6;
    char* base = (char*)&sA[kt & 1][h * 8192];
#pragma unroll
    for (int it = 0; it < 2; ++it) {
      const int f = tid + it * 512;
      const int r = f >> 3, c = f & 7;
      gload16(Ap + (rowA + h * 128 + r) * Kstride + k0 + ((c ^ (r & 7)) << 3), base + f * 16);
    }
  };
  auto stageB = [&](int kt, int h) {
    if (kt >= nkt) return;
    const int k0 = kt << 6;
    char* base = (char*)&sB[kt & 1][h * 8192];
#pragma unroll
    for (int it = 0; it < 2; ++it) {
      const int f = tid + it * 512;
      const int r = f >> 3, c = f & 7;
      gload16(Btp + (rowB + h * 128 + r) * Kstride + k0 + ((c ^ (r & 7)) << 3), base + f * 16);
    }
  };

  stageA(0, 0); stageB(0, 0); stageA(0, 1); stageB(0, 1);
  stageB(1, 0); stageA(1, 0);
  asm volatile("s_waitcnt vmcnt(4)" ::: "memory");
  __builtin_amdgcn_s_barrier();
  asm volatile("" ::: "memory");

  bf16x8 a[4][2], b[4][2];
  for (int kt = 0; kt < nkt; ++kt) {
    const u16* bufA = &sA[kt & 1][0];
    const u16* bufB = &sB[kt & 1][0];
#pragma unroll
    for (int m = 0; m < 4; ++m)
#pragma unroll
      for (int kk = 0; kk < 2; ++kk) {
        const int r = wr * 128 + m * 16 + l16;
        a[m][kk] = *reinterpret_cast<const bf16x8*>(bufA + r * 64 + (((kk * 4 + lg) ^ (r & 7)) << 3));
      }
#pragma unroll
    for (int n = 0; n < 2; ++n)
#pragma unroll
      for (int kk = 0; kk < 2; ++kk) {
        const int r = wc * 64 + n * 16 + l16;
        b[n][kk] = *reinterpret_cast<const bf16x8*>(bufB + r * 64 + (((kk * 4 + lg) ^ (r & 7)) << 3));
      }
    stageB(kt + 1, 1);
    __builtin_amdgcn_s_barrier();
    asm volatile("s_waitcnt lgkmcnt(0)" ::: "memory");
    __builtin_amdgcn_s_setprio(1);
#pragma unroll
    for (int kk = 0; kk < 2; ++kk)
#pragma unroll
      for (int m = 0; m < 4; ++m)
#pragma unroll
        for (int n = 0; n < 2; ++n)
          acc[m][n] = MFMA16(a[m][kk], b[n][kk], acc[m][n]);
    __builtin_amdgcn_s_setprio(0);
    __builtin_amdgcn_s_barrier();
    asm volatile("" ::: "memory");
#pragma unroll
    for (int n = 2; n < 4; ++n)
#pragma unroll
      for (int kk = 0; kk < 2; ++kk) {
        const int r = wc * 64 + n * 16 + l16;
        b[n][kk] = *reinterpret_cast<const bf16x8*>(bufB + r * 64 + (((kk * 4 + lg) ^ (r & 7)) << 3));
      }
    stageA(kt + 1, 1);
    __builtin_amdgcn_s_barrier();
    asm volatile("s_waitcnt lgkmcnt(0)" ::: "memory");
    __builtin_amdgcn_s_setprio(1);
#pragma unroll
    for (int kk = 0; kk < 2; ++kk)
#pragma unroll
      for (int m = 0; m < 4; ++m)
#pragma unroll
        for (int n = 2; n < 4; ++n)
          acc[m][n] = MFMA16(a[m][kk], b[n][kk], acc[m][n]);
    __builtin_amdgcn_s_setprio(0);
    __builtin_amdgcn_s_barrier();
    asm volatile("" ::: "memory");
#pragma unroll
    for (int m = 0; m < 4; ++m)
#pragma unroll
      for (int kk = 0; kk < 2; ++kk) {
        const int r = wr * 128 + 64 + m * 16 + l16;
        a[m][kk] = *reinterpret_cast<const bf16x8*>(bufA + r * 64 + (((kk * 4 + lg) ^ (r & 7)) << 3));
      }
    stageB(kt + 2, 0);
    __builtin_amdgcn_s_barrier();
    asm volatile("s_waitcnt lgkmcnt(0)" ::: "memory");
    __builtin_amdgcn_s_setprio(1);
#pragma unroll
    for (int kk = 0; kk < 2; ++kk)
#pragma unroll
      for (int m = 0; m < 4; ++m)
#pragma unroll
        for (int n = 2; n < 4; ++n)
          acc[4 + m][n] = MFMA16(a[m][kk], b[n][kk], acc[4 + m][n]);
    __builtin_amdgcn_s_setprio(0);
    __builtin_amdgcn_s_barrier();
    asm volatile("" ::: "memory");
    stageA(kt + 2, 0);
    __builtin_amdgcn_s_setprio(1);
#pragma unroll
    for (int kk = 0; kk < 2; ++kk)
#pragma unroll
      for (int m = 0; m < 4; ++m)
#pragma unroll
        for (int n = 0; n < 2; ++n)
          acc[4 + m][n] = MFMA16(a[m][kk], b[n][kk], acc[4 + m][n]);
    __builtin_amdgcn_s_setprio(0);
    if (kt + 2 < nkt) {
      asm volatile("s_waitcnt vmcnt(4)" ::: "memory");
    } else {
      asm volatile("s_waitcnt vmcnt(0)" ::: "memory");  // tail: stages skipped, full drain
    }
    __builtin_amdgcn_s_barrier();
    asm volatile("" ::: "memory");
  }

#pragma unroll
  for (int m = 0; m < 8; ++m)
#pragma unroll
    for (int n = 0; n < 4; ++n)
#pragma unroll
      for (int ii = 0; ii < 4; ++ii) {
        const int gi = bm * 256 + wr * 128 + m * 16 + lg * 4 + ii;
        const int gj = bn * 256 + wc * 64 + n * 16 + l16;
        const float val = acc[m][n][ii];
        if constexpr (EPI == EPI_QKV) {
          const int sel = gj >> 10;          // 0:q 1:k 2:v
          const int hh = (gj >> 6) & 15;
          const int dd = gj & 63;
          const int bb = gi >> 11, tt = gi & 2047;
          const float sv = (sel == 0) ? val * 0.1803368801f : val;
          outB[(size_t)sel * 8388608 + ((size_t)(bb * 16 + hh) * 2048 + tt) * 64 + dd] = f2bf(sv);
        } else if constexpr (EPI == EPI_RELU) {
          const float bv = val + bias[gj];
          outB[(size_t)gi * N + gj] = f2bf(bv > 0.f ? bv : 0.f);
        } else if constexpr (EPI == EPI_PART) {
          outp[(size_t)gi * N + gj] = f2bf(val);
        }
      }
}

// ---------------- GEMM 128x256 tile, BK=64, 8 waves, 8-phase (proj) ------
template <int EPI>
__global__ __launch_bounds__(512) void gemm128(
    const u16* __restrict__ A, const u16* __restrict__ Bt,
    int M, int N, int K, int NBN,
    u16* outB, float* outF, const float* bias, const float* res) {
  __shared__ u16 sA[2][128 * 64] __attribute__((aligned(16)));  // 32KB
  __shared__ u16 sB[2][256 * 64] __attribute__((aligned(16)));  // 64KB
  const int tid = threadIdx.x;
  const int lane = tid & 63, wid = tid >> 6;
  const int wr = wid >> 2, wc = wid & 3;  // 2 x 4 wave grid; wave out 64x64
  const int l16 = lane & 15, lg = lane >> 4;
  const int nwg = gridDim.x;
  const int wgid = (blockIdx.x & 7) * (nwg >> 3) + (blockIdx.x >> 3);
  const int bm = wgid / NBN, bn = wgid % NBN;
  const size_t rowA = (size_t)bm * 128;
  const size_t rowB = (size_t)bn * 256;
  const int nkt = K >> 6;

  f32x4 acc[4][4];
#pragma unroll
  for (int m = 0; m < 4; ++m)
#pragma unroll
    for (int n = 0; n < 4; ++n) {
      acc[m][n][0] = 0.f; acc[m][n][1] = 0.f; acc[m][n][2] = 0.f; acc[m][n][3] = 0.f;
    }

  auto stageA = [&](int kt, int h) {  // 64 rows x 64 cols: 1 load/thread
    if (kt >= nkt) return;
    const int k0 = kt << 6;
    char* base = (char*)&sA[kt & 1][h * 4096];
    const int r = tid >> 3, c = tid & 7;
    gload16(A + (rowA + h * 64 + r) * K + k0 + ((c ^ (r & 7)) << 3), base + tid * 16);
  };
  auto stageB = [&](int kt, int h) {  // 128 rows x 64 cols: 2 loads/thread
    if (kt >= nkt) return;
    const int k0 = kt << 6;
    char* base = (char*)&sB[kt & 1][h * 8192];
#pragma unroll
    for (int it = 0; it < 2; ++it) {
      const int f = tid + it * 512;
      const int r = f >> 3, c = f & 7;
      gload16(Bt + (rowB + h * 128 + r) * K + k0 + ((c ^ (r & 7)) << 3), base + f * 16);
    }
  };

  stageA(0, 0); stageB(0, 0); stageA(0, 1); stageB(0, 1);
  stageB(1, 0); stageA(1, 0);
  asm volatile("s_waitcnt vmcnt(3)" ::: "memory");
  __builtin_amdgcn_s_barrier();
  asm volatile("" ::: "memory");

  bf16x8 a[2][2], b[4][2];
  for (int kt = 0; kt < nkt; ++kt) {
    const u16* bufA = &sA[kt & 1][0];
    const u16* bufB = &sB[kt & 1][0];
#pragma unroll
    for (int m = 0; m < 2; ++m)
#pragma unroll
      for (int kk = 0; kk < 2; ++kk) {
        const int r = wr * 64 + m * 16 + l16;
        a[m][kk] = *reinterpret_cast<const bf16x8*>(bufA + r * 64 + (((kk * 4 + lg) ^ (r & 7)) << 3));
      }
#pragma unroll
    for (int n = 0; n < 2; ++n)
#pragma unroll
      for (int kk = 0; kk < 2; ++kk) {
        const int r = wc * 64 + n * 16 + l16;
        b[n][kk] = *reinterpret_cast<const bf16x8*>(bufB + r * 64 + (((kk * 4 + lg) ^ (r & 7)) << 3));
      }
    stageB(kt + 1, 1);
    __builtin_amdgcn_s_barrier();
    asm volatile("s_waitcnt lgkmcnt(0)" ::: "memory");
    __builtin_amdgcn_s_setprio(1);
#pragma unroll
    for (int kk = 0; kk < 2; ++kk)
#pragma unroll
      for (int m = 0; m < 2; ++m)
#pragma unroll
        for (int n = 0; n < 2; ++n)
          acc[m][n] = MFMA16(a[m][kk], b[n][kk], acc[m][n]);
    __builtin_amdgcn_s_setprio(0);
    __builtin_amdgcn_s_barrier();
    asm volatile("" ::: "memory");
#pragma unroll
    for (int n = 2; n < 4; ++n)
#pragma unroll
      for (int kk = 0; kk < 2; ++kk) {
        const int r = wc * 64 + n * 16 + l16;
        b[n][kk] = *reinterpret_cast<const bf16x8*>(bufB + r * 64 + (((kk * 4 + lg) ^ (r & 7)) << 3));
      }
    stageA(kt + 1, 1);
    __builtin_amdgcn_s_barrier();
    asm volatile("s_waitcnt lgkmcnt(0)" ::: "memory");
    __builtin_amdgcn_s_setprio(1);
#pragma unroll
    for (int kk = 0; kk < 2; ++kk)
#pragma unroll
      for (int m = 0; m < 2; ++m)
#pragma unroll
        for (int n = 2; n < 4; ++n)
          acc[m][n] = MFMA16(a[m][kk], b[n][kk], acc[m][n]);
    __builtin_amdgcn_s_setprio(0);
    __builtin_amdgcn_s_barrier();
    asm volatile("" ::: "memory");
#pragma unroll
    for (int m = 0; m < 2; ++m)
#pragma unroll
      for (int kk = 0; kk < 2; ++kk) {
        const int r = wr * 64 + (m + 2) * 16 + l16;
        a[m][kk] = *reinterpret_cast<const bf16x8*>(bufA + r * 64 + (((kk * 4 + lg) ^ (r & 7)) << 3));
      }
    stageB(kt + 2, 0);
    __builtin_amdgcn_s_barrier();
    asm volatile("s_waitcnt lgkmcnt(0)" ::: "memory");
    __builtin_amdgcn_s_setprio(1);
#pragma unroll
    for (int kk = 0; kk < 2; ++kk)
#pragma unroll
      for (int m = 0; m < 2; ++m)
#pragma unroll
        for (int n = 2; n < 4; ++n)
          acc[2 + m][n] = MFMA16(a[m][kk], b[n][kk], acc[2 + m][n]);
    __builtin_amdgcn_s_setprio(0);
    __builtin_amdgcn_s_barrier();
    asm volatile("" ::: "memory");
    stageA(kt + 2, 0);
    __builtin_amdgcn_s_setprio(1);
#pragma unroll
    for (int kk = 0; kk < 2; ++kk)
#pragma unroll
      for (int m = 0; m < 2; ++m)
#pragma unroll
        for (int n = 0; n < 2; ++n)
          acc[2 + m][n] = MFMA16(a[m][kk], b[n][kk], acc[2 + m][n]);
    __builtin_amdgcn_s_setprio(0);
    if (kt + 2 < nkt) {
      asm volatile("s_waitcnt vmcnt(3)" ::: "memory");
    } else {
      asm volatile("s_waitcnt vmcnt(0)" ::: "memory");  // tail: full drain
    }
    __builtin_amdgcn_s_barrier();
    asm volatile("" ::: "memory");
  }

#pragma unroll
  for (int m = 0; m < 4; ++m)
#pragma unroll
    for (int n = 0; n < 4; ++n)
#pragma unroll
      for (int ii = 0; ii < 4; ++ii) {
        const int gi = bm * 128 + wr * 64 + m * 16 + lg * 4 + ii;
        const int gj = bn * 256 + wc * 64 + n * 16 + l16;
        const float val = acc[m][n][ii];
        if constexpr (EPI == EPI_RES) {
          const size_t idx = (size_t)gi * N + gj;
          outF[idx] = val + bias[gj] + res[idx];
        }
      }
}

// ---------------- causal flash attention v8: round-11 best (REVERT of v9) --------
// v5 schedule + T13 defer-max. 1024 blocks, QTAB-balanced, 3 blocks/CU, 80 VGPR.
__device__ __constant__ int QTAB[16] = {15, 14, 13, 12, 11, 10, 9, 8,
                                        4, 5, 6, 7, 0, 1, 2, 3};

__global__ __launch_bounds__(256, 3) void attn_kernel(
    const u16* __restrict__ q, const u16* __restrict__ k,
    const u16* __restrict__ v, u16* __restrict__ o) {
  const int bid = blockIdx.x;
  const int bh = (bid & 7) * 8 + ((bid >> 3) & 7);  // 8 bh per XCD -> K/V L2-resident
  const int qt = QTAB[bid >> 6];                    // balanced static CU load
  const int tid = threadIdx.x;
  const int lane = tid & 63, wid = tid >> 6;
  const int l32 = lane & 31, hi = lane >> 5;
  const u16* qb = q + (size_t)bh * (2048 * 64);
  const u16* kb = k + (size_t)bh * (2048 * 64);
  const u16* vb = v + (size_t)bh * (2048 * 64);
  const int q0 = qt * 128;
  const int qrow = q0 + wid * 32 + l32;  // this lane's q row

  __shared__ u16 sK[2][64 * 64] __attribute__((aligned(16)));   // chunk-xor swizzled
  __shared__ u16 sVt[2][64 * 72] __attribute__((aligned(16)));  // V^T [d][kv], pad 72

  bf16x8 bq[4];
#pragma unroll
  for (int s = 0; s < 4; ++s)
    bq[s] = *reinterpret_cast<const bf16x8*>(qb + (size_t)qrow * 64 + s * 16 + hi * 8);

  // ones-row A fragment for the li-sum MFMA (row 0 of the 32x32 tile)
  bf16x8 aone;
  {
    union { u16 u[8]; bf16x8 v; } onec;
    const u16 ov = (l32 == 0) ? (u16)0x3F80 : (u16)0;
#pragma unroll
    for (int j = 0; j < 8; ++j) onec.u[j] = ov;
    aone = onec.v;
  }

  f32x16 oacc[2], osum;
#pragma unroll
  for (int r = 0; r < 16; ++r) { oacc[0][r] = 0.f; oacc[1][r] = 0.f; osum[r] = 0.f; }
  float mi = -1e30f;

  uint4 vr0, vr1;  // V staging regs

  auto stageK = [&](int s0, int buf) {
#pragma unroll
    for (int it = 0; it < 2; ++it) {
      const int f = tid + it * 256;  // 16B-chunk index in [64][8]
      const int r = f >> 3, c = f & 7;
      gload16(kb + (size_t)(s0 + r) * 64 + (size_t)((c ^ (r & 7)) * 8),
              (char*)&sK[buf][0] + it * 4096 + wid * 1024);
    }
  };
  auto loadV = [&](int s0) {
    const int kvp = tid & 31;  // kv row-pair
    const int c8 = tid >> 5;   // d-chunk
    vr0 = *reinterpret_cast<const uint4*>(vb + (size_t)(s0 + 2 * kvp) * 64 + c8 * 8);
    vr1 = *reinterpret_cast<const uint4*>(vb + (size_t)(s0 + 2 * kvp + 1) * 64 + c8 * 8);
  };
  auto writeV = [&](int buf) {
    const int kvp = tid & 31;
    const int c8 = tid >> 5;
    const u16* e0 = reinterpret_cast<const u16*>(&vr0);
    const u16* e1 = reinterpret_cast<const u16*>(&vr1);
    u16* base = &sVt[buf][0];
#pragma unroll
    for (int j = 0; j < 8; ++j) {
      const int d = c8 * 8 + j;
      *reinterpret_cast<uint32_t*>(base + d * 72 + 2 * kvp) =
          (uint32_t)e0[j] | ((uint32_t)e1[j] << 16);
    }
  };

  const int nst = 2 * qt + 2;  // always even, >= 2
  stageK(0, 0);
  loadV(0);
  asm volatile("s_waitcnt vmcnt(0)" ::: "memory");
  writeV(0);
  __syncthreads();

  int cur = 0;
  for (int ks = 0; ks < nst; ++ks) {
    const int s0 = ks * 64;
    const int nxt = cur ^ 1;
    if (ks + 1 < nst) { stageK(s0 + 64, nxt); loadV(s0 + 64); }

    // ---- S^T = K Q^T ----
    f32x16 st[2];
#pragma unroll
    for (int r = 0; r < 16; ++r) { st[0][r] = 0.f; st[1][r] = 0.f; }
    __builtin_amdgcn_s_setprio(1);
#pragma unroll
    for (int t = 0; t < 2; ++t) {
      const int row = t * 32 + l32;
      const int rx = row & 7;
#pragma unroll
      for (int s = 0; s < 4; ++s) {
        bf16x8 ak = *reinterpret_cast<const bf16x8*>(
            &sK[cur][0] + row * 64 + (((s * 2 + hi) ^ rx) << 3));
        st[t] = MFMA32(ak, bq[s], st[t]);
      }
    }
    __builtin_amdgcn_s_setprio(0);

    // ---- causal mask (only near diagonal) ----
    if (ks >= 2 * qt) {
#pragma unroll
      for (int t = 0; t < 2; ++t)
#pragma unroll
        for (int a = 0; a < 4; ++a)
#pragma unroll
          for (int c2 = 0; c2 < 4; ++c2) {
            const int kvg = s0 + t * 32 + a * 8 + hi * 4 + c2;
            if (kvg > qrow) st[t][a * 4 + c2] = -1e30f;
          }
    }

    // ---- online softmax: tree max; T13 defer-max (THR=8, exp2 domain) ----
    float tm[16];
#pragma unroll
    for (int r = 0; r < 16; ++r) tm[r] = fmaxf(st[0][r], st[1][r]);
#pragma unroll
    for (int s2 = 8; s2 >= 1; s2 >>= 1)
#pragma unroll
      for (int r = 0; r < s2; ++r) tm[r] = fmaxf(tm[r], tm[r + s2]);
    const float pm = fmaxf(tm[0], __shfl_xor(tm[0], 32));
    // rescale only when the max grew by >8 (P bounded by 2^8; li <= 2048*256, fp32-safe)
    if (__any(pm > mi + 8.0f)) {
      const float mn = fmaxf(mi, pm);
      const float al = exp2f(mi - mn);
      mi = mn;
      osum[0] *= al;
#pragma unroll
      for (int dt = 0; dt < 2; ++dt)
#pragma unroll
        for (int r = 0; r < 16; ++r) oacc[dt][r] *= al;
    }
#pragma unroll
    for (int t = 0; t < 2; ++t)
#pragma unroll
      for (int r = 0; r < 16; ++r) st[t][r] = exp2f(st[t][r] - mi);

    // ---- P^T -> bf16 B-frags in-register; PV + li-sum via MFMA ----
    uint32_t W[2][4][2];
#pragma unroll
    for (int t = 0; t < 2; ++t)
#pragma unroll
      for (int a = 0; a < 4; ++a) {
        W[t][a][0] = cvtpk(st[t][a * 4 + 0], st[t][a * 4 + 1]);
        W[t][a][1] = cvtpk(st[t][a * 4 + 2], st[t][a * 4 + 3]);
      }
    __builtin_amdgcn_s_setprio(1);
#pragma unroll
    for (int ks2 = 0; ks2 < 4; ++ks2) {
      const int t = ks2 >> 1;
      uint32_t A0 = W[t][(2 * ks2) & 3][0], B0 = W[t][(2 * ks2 + 1) & 3][0];
      uint32_t A1 = W[t][(2 * ks2) & 3][1], B1 = W[t][(2 * ks2 + 1) & 3][1];
      pl32swap(A0, B0);
      pl32swap(A1, B1);
      union { uint32_t w[4]; bf16x8 v; } bp;
      bp.w[0] = A0; bp.w[1] = A1; bp.w[2] = B0; bp.w[3] = B1;
#pragma unroll
      for (int dt = 0; dt < 2; ++dt) {
        bf16x8 av = *reinterpret_cast<const bf16x8*>(
            &sVt[cur][0] + (dt * 32 + l32) * 72 + ks2 * 16 + hi * 8);
        oacc[dt] = MFMA32(av, bp.v, oacc[dt]);
      }
      osum = MFMA32(aone, bp.v, osum);  // row 0 = sum_kv P -> li
    }
    __builtin_amdgcn_s_setprio(0);

    if (ks + 1 < nst) {
      asm volatile("s_waitcnt vmcnt(0)" ::: "memory");  // K gload_lds + V regs landed
      writeV(nxt);
      __syncthreads();
    }
    cur = nxt;
  }

  // ---- epilogue: O^T regs -> [B,T,C] bf16, /li ----
  const float li = __shfl(osum[0], l32);  // row 0, col q=l32 lives in lane l32 (hi=0)
  const int bb = bh >> 4, hh = bh & 15;
  const float rli = 1.0f / li;
  const size_t rowo = (size_t)(bb * 2048 + qrow) * 1024;
#pragma unroll
  for (int dt = 0; dt < 2; ++dt)
#pragma unroll
    for (int a = 0; a < 4; ++a) {
      ushort4 pk;
      pk.x = f2bf(oacc[dt][a * 4 + 0] * rli);
      pk.y = f2bf(oacc[dt][a * 4 + 1] * rli);
      pk.z = f2bf(oacc[dt][a * 4 + 2] * rli);
      pk.w = f2bf(oacc[dt][a * 4 + 3] * rli);
      *reinterpret_cast<ushort4*>(o + rowo + hh * 64 + dt * 32 + a * 8 + hi * 4) = pk;
    }
}

// ---------------- host launch ----------------
extern "C" void kernel_launch(void* const* d_in, const int* in_sizes, int n_in,
                              void* d_out, int out_size, void* d_ws, size_t ws_size,
                              hipStream_t stream) {
  const float* x = (const float*)d_in[0];
  const float* Wq = (const float*)d_in[1];
  const float* Wk = (const float*)d_in[2];
  const float* Wv = (const float*)d_in[3];
  const float* Wproj = (const float*)d_in[4];
  const float* bproj = (const float*)d_in[5];
  const float* W1 = (const float*)d_in[6];
  const float* b1 = (const float*)d_in[7];
  const float* W2 = (const float*)d_in[8];
  const float* b2 = (const float*)d_in[9];
  const float* g1 = (const float*)d_in[10];
  const float* be1 = (const float*)d_in[11];
  const float* g2 = (const float*)d_in[12];
  const float* be2 = (const float*)d_in[13];
  float* out = (float*)d_out;

  char* ws = (char*)d_ws;
  const size_t MB16 = 16777216ull;
  u16* hb = (u16*)(ws);                 // 16MB: ln out (reused for ln2 out)
  u16* qkv = (u16*)(ws + MB16);         // 48MB: q,k,v each 8388608 elems
  u16* qp = qkv;
  u16* kp = qkv + 8388608;
  u16* vp = qkv + 2 * 8388608;
  u16* ab = (u16*)(ws + 4 * MB16);      // 16MB: attention out [B,T,C]
  u16* f1 = qkv;                        // 64MB reuse (16MB..80MB) for relu(ff1)
  u16* wqkvt = (u16*)(ws + 5 * MB16);   // 6MB  [3072][1024]
  u16* wprojt = wqkvt + 3145728;        // 2MB  [1024][1024]
  u16* w1t = wprojt + 1048576;          // 8MB  [4096][1024]
  u16* w2t = w1t + 4194304;             // 8MB  [1024][4096]
  // split-K partials (live only during FF2; alias buffers dead by then)
  u16* p0 = hb;                         // 16MB (hb dead after FF1 reads it)
  u16* p1 = wqkvt;                      // 16MB (wqkvt+wprojt+w1t dead after FF1)

  dim3 blk(256);
  // fused: ln1 (8192 blocks) + all weight transposes (3072 blocks)
  prep<<<11264, blk, 0, stream>>>(x, g1, be1, hb, Wq, Wk, Wv, Wproj, W1, W2,
                                  wqkvt, wprojt, w1t, w2t);
  gemm256<EPI_QKV><<<384, 512, 0, stream>>>(hb, wqkvt, 8192, 3072, 1024, 1024, 12, 0,
                                            qkv, nullptr, nullptr, nullptr);
  attn_kernel<<<1024, blk, 0, stream>>>(qp, kp, vp, ab);
  gemm128<EPI_RES><<<256, 512, 0, stream>>>(ab, wprojt, 8192, 1024, 1024, 4,
                                            nullptr, out, bproj, x);
  ln_kernel<<<8192, blk, 0, stream>>>(out, g2, be2, hb);
  gemm256<EPI_RELU><<<512, 512, 0, stream>>>(hb, w1t, 8192, 4096, 1024, 1024, 16, 0,
                                             f1, nullptr, nullptr, b1);
  // FF2 split-K: two K=2048 halves at full occupancy, bf16 partials, then combine
  gemm256<EPI_PART><<<256, 512, 0, stream>>>(f1, w2t, 8192, 1024, 2048, 4096, 4, 1,
                                             p0, p1, nullptr, nullptr);
  ff2_combine<<<4096, blk, 0, stream>>>(p0, p1, b2, out);
}